// Round 6
// baseline (197.287 us; speedup 1.0000x reference)
//
#include <hip/hip_runtime.h>

// KAN layer fused as one augmented GEMM:
//   out[n][o] = sum_i silu(x[n][i])*scale_base[o][i]
//            + sum_{i,m} basis_m(x[n][i])*scale_sp[o][i]*coef[o][i][m] + bias[o]
// A_aug (8192 x 5376) f16, W_aug (768 x 5376) f16, k = j*768 + i (j=0: silu, j=1..6: basis)
//
// GEMM: 128x192 tile, BK=64, 512 thr (8 waves 2Mx4N, wave tile 64x48), grid=256
// = exactly 1 block/CU. Triple-buffered LDS + counted vmcnt(5) (T3+T4) + setprio
// (T5) + source-side XOR slot swizzle (T2) + XCD-chunked block swizzle (T1).
// R6: ONE barrier per K-tile (mid-tile barrier removed -- triple buffer makes it
// redundant): region = stage(t+2) | 14 ds_read | 24 MFMA | lgkmcnt(0) vmcnt(5) | bar.
// LDS-read burst (1344 cyc/CU) now overlaps the MFMA stream (931 cyc/SIMD)
// instead of serializing phase-by-phase behind two barriers.

typedef _Float16 f16;
typedef __attribute__((ext_vector_type(2))) _Float16 f16x2;
typedef __attribute__((ext_vector_type(4))) _Float16 f16x4;
typedef __attribute__((ext_vector_type(8))) _Float16 f16x8;
typedef __attribute__((ext_vector_type(4))) float f32x4;

#define NTOK 8192
#define DIN 768
#define DOUT 768
#define KAUG 5376        // 7*768
#define BM 128
#define BN 192
#define BK 64
#define NKT (KAUG / BK)  // 84 K-tiles
#define ASZ (BM * BK)    // 8192 f16 = 16 KB
#define BSZ (BN * BK)    // 12288 f16 = 24 KB
#define NBLK ((NTOK / BM) * (DOUT / BN))  // 64*4 = 256 blocks

typedef __attribute__((address_space(1))) void gvoid;
typedef __attribute__((address_space(3))) void lvoid;

// ---------------- silu + 6 basis values for one x ----------------
__device__ __forceinline__ void spline6(float xv, float* __restrict__ B, float& s) {
  s = xv / (1.0f + __expf(-xv));  // silu
  const float h = 2.0f / 3.0f;
  float Bb[9];
#pragma unroll
  for (int g = 0; g < 9; ++g) {
    float t0 = (float)(g - 3) * h - 1.0f;
    float t1 = (float)(g - 2) * h - 1.0f;
    Bb[g] = (xv >= t0 && xv < t1) ? 1.0f : 0.0f;
  }
#pragma unroll
  for (int p = 1; p <= 3; ++p) {
    float inv = 1.0f / ((float)p * h);
#pragma unroll
    for (int j = 0; j < 8; ++j) {
      if (j < 9 - p) {
        float tj = (float)(j - 3) * h - 1.0f;
        float tjp1 = (float)(j + p + 1 - 3) * h - 1.0f;
        Bb[j] = (xv - tj) * inv * Bb[j] + (tjp1 - xv) * inv * Bb[j + 1];
      }
    }
  }
#pragma unroll
  for (int m = 0; m < 6; ++m) B[m] = Bb[m];
}

#define NBLK_A ((NTOK * DIN) / 1024)  // 6144 (x4-vectorized, 256 thr)
#define NBLK_W ((DOUT * DIN) / 512)   // 1152 (x2-vectorized, 256 thr)

// ---------------- Kernel 1: fused build of A_aug and W_aug ----------------
__global__ __launch_bounds__(256) void build_AW(const float* __restrict__ x,
                                                const float* __restrict__ sb,
                                                const float* __restrict__ ssp,
                                                const float* __restrict__ coef,
                                                f16* __restrict__ Aa,
                                                f16* __restrict__ Wa) {
  const int b = blockIdx.x;
  if (b < NBLK_A) {
    int idx = (b * 256 + threadIdx.x) * 4;  // 4 consecutive i, same n (DIN%4==0)
    float4 xv = *(const float4*)(x + idx);
    int n = idx / DIN;
    int i = idx - n * DIN;

    float B0[6], B1[6], B2[6], B3[6];
    float s0, s1, s2, s3;
    spline6(xv.x, B0, s0);
    spline6(xv.y, B1, s1);
    spline6(xv.z, B2, s2);
    spline6(xv.w, B3, s3);

    size_t base = (size_t)n * KAUG + i;
    f16x4 sv = {(f16)s0, (f16)s1, (f16)s2, (f16)s3};
    *(f16x4*)(Aa + base) = sv;
#pragma unroll
    for (int m = 0; m < 6; ++m) {
      f16x4 bv = {(f16)B0[m], (f16)B1[m], (f16)B2[m], (f16)B3[m]};
      *(f16x4*)(Aa + base + (size_t)(m + 1) * DIN) = bv;
    }
  } else {
    int idx2 = ((b - NBLK_A) * 256 + threadIdx.x) * 2;  // (o,i) and (o,i+1)
    float2 bb = *(const float2*)(sb + idx2);
    float2 pp = *(const float2*)(ssp + idx2);
    int o = idx2 / DIN;
    int i = idx2 - o * DIN;
    size_t base = (size_t)o * KAUG + i;
    f16x2 w0 = {(f16)bb.x, (f16)bb.y};
    *(f16x2*)(Wa + base) = w0;
    float4 c0 = *(const float4*)(coef + (size_t)idx2 * 6);
    float4 c1 = *(const float4*)(coef + (size_t)idx2 * 6 + 4);
    float4 c2 = *(const float4*)(coef + (size_t)idx2 * 6 + 8);
    float ma[6] = {c0.x, c0.y, c0.z, c0.w, c1.x, c1.y};
    float mb[6] = {c1.z, c1.w, c2.x, c2.y, c2.z, c2.w};
#pragma unroll
    for (int m = 0; m < 6; ++m) {
      f16x2 wv = {(f16)(pp.x * ma[m]), (f16)(pp.y * mb[m])};
      *(f16x2*)(Wa + base + (size_t)(m + 1) * DIN) = wv;
    }
  }
}

// ---------------- Kernel 2: GEMM C = A_aug * W_aug^T + bias ----------------
// LDS content: buf[row][slot] = G[row][slot ^ (row&7)] (slot = 8-f16 group of K).
// global_load_lds dest linear (chunk c -> 16B at c*16); per-lane GLOBAL src is
// pre-swizzled. Reads apply the same XOR -> conflict-free.
// Hazard audit for the 1-barrier schedule (3 buffers):
//  - STAGE(t+2) overwrites buf (t-1)%3: all waves' reads(t-1) completed before
//    the barrier ending tile t-1 (explicit lgkmcnt(0)), STAGE is after it. OK.
//  - reads(t) need stage(t) landed FOR ALL WAVES: each wave passes
//    lgkmcnt(0)+vmcnt(5) (own stage(t) landed; 5 newest = own stage(t+1))
//    before the barrier -> collective after the barrier. OK.
__global__ __launch_bounds__(512, 2) void kan_gemm(const f16* __restrict__ A,
                                                   const f16* __restrict__ W,
                                                   const float* __restrict__ bias,
                                                   float* __restrict__ out) {
  __shared__ alignas(16) f16 As[3 * ASZ];  // 48 KB
  __shared__ alignas(16) f16 Bs[3 * BSZ];  // 72 KB  (120 KB total, 1 block/CU)

  const int tid = threadIdx.x;
  const int wave = tid >> 6;
  const int lane = tid & 63;

  // XCD-chunked swizzle: 256 % 8 == 0 -> bijective. Each XCD: 8 M-panels x 4 cols.
  const int bid = blockIdx.x;
  const int wg = (bid & 7) * (NBLK / 8) + (bid >> 3);
  const int m0 = (wg >> 2) * BM;
  const int n0 = (wg & 3) * BN;

  const int wm = (wave >> 2) * 64;  // 2 M-waves
  const int wn = (wave & 3) * 48;   // 4 N-waves
  const int r = lane & 15;
  const int q = lane >> 4;
  const int r7 = r & 7;

  f32x4 acc[4][3] = {};

  // ---- staging source pointers (chunk c: row = c>>3, lds slot = c&7,
  //      global slot = (c&7) ^ (row&7)) ----
  const int cA0 = tid, cA1 = tid + 512;
  const int cB0 = tid, cB1 = tid + 512, cB2 = tid + 1024;
  const f16* gA0 = A + (size_t)(m0 + (cA0 >> 3)) * KAUG + ((cA0 & 7) ^ ((cA0 >> 3) & 7)) * 8;
  const f16* gA1 = A + (size_t)(m0 + (cA1 >> 3)) * KAUG + ((cA1 & 7) ^ ((cA1 >> 3) & 7)) * 8;
  const f16* gB0 = W + (size_t)(n0 + (cB0 >> 3)) * KAUG + ((cB0 & 7) ^ ((cB0 >> 3) & 7)) * 8;
  const f16* gB1 = W + (size_t)(n0 + (cB1 >> 3)) * KAUG + ((cB1 & 7) ^ ((cB1 >> 3) & 7)) * 8;
  const f16* gB2 = W + (size_t)(n0 + (cB2 >> 3)) * KAUG + ((cB2 & 7) ^ ((cB2 >> 3) & 7)) * 8;
  // wave-uniform LDS dests (f16 units); HW adds lane*16B
  const int dA0 = wave * 512, dA1 = 4096 + wave * 512;
  const int dB0 = wave * 512, dB1 = 4096 + wave * 512, dB2 = 8192 + wave * 512;

#define STAGE_B(bufi, kt)                                                                  \
  do {                                                                                     \
    const int ko = (kt)*BK;                                                                \
    f16* bb_ = Bs + (bufi)*BSZ;                                                            \
    __builtin_amdgcn_global_load_lds((gvoid*)(gB0 + ko), (lvoid*)(bb_ + dB0), 16, 0, 0);   \
    __builtin_amdgcn_global_load_lds((gvoid*)(gB1 + ko), (lvoid*)(bb_ + dB1), 16, 0, 0);   \
    __builtin_amdgcn_global_load_lds((gvoid*)(gB2 + ko), (lvoid*)(bb_ + dB2), 16, 0, 0);   \
  } while (0)

#define STAGE_A(bufi, kt)                                                                  \
  do {                                                                                     \
    const int ko = (kt)*BK;                                                                \
    f16* ab_ = As + (bufi)*ASZ;                                                            \
    __builtin_amdgcn_global_load_lds((gvoid*)(gA0 + ko), (lvoid*)(ab_ + dA0), 16, 0, 0);   \
    __builtin_amdgcn_global_load_lds((gvoid*)(gA1 + ko), (lvoid*)(ab_ + dA1), 16, 0, 0);   \
  } while (0)

  // prologue: stage tiles 0 and 1 (issue order matters for vmcnt accounting)
  STAGE_B(0, 0);
  STAGE_A(0, 0);
  STAGE_B(1, 1);
  STAGE_A(1, 1);
  asm volatile("s_waitcnt vmcnt(5)" ::: "memory");  // own tile-0 loads landed
  __builtin_amdgcn_sched_barrier(0);
  __builtin_amdgcn_s_barrier();                     // -> collective: tile 0 in LDS

  for (int t = 0; t < NKT; ++t) {
    const int rb = t % 3;
    const f16* Ab = As + rb * ASZ;
    const f16* Bb = Bs + rb * BSZ;

    if (t + 2 < NKT) {  // prefetch tile t+2 (5 loads, stay in flight past barrier)
      const int pb = (t + 2) % 3;
      STAGE_B(pb, t + 2);
      STAGE_A(pb, t + 2);
    }

    // all 14 fragment reads for this tile (both K-halves)
    f16x8 af[2][4], bf[2][3];
#pragma unroll
    for (int kh = 0; kh < 2; ++kh) {
      const int sl = ((kh * 4 + q) ^ r7) * 8;
#pragma unroll
      for (int mi = 0; mi < 4; ++mi)
        af[kh][mi] = *(const f16x8*)&Ab[(wm + mi * 16 + r) * BK + sl];
#pragma unroll
      for (int ni = 0; ni < 3; ++ni)
        bf[kh][ni] = *(const f16x8*)&Bb[(wn + ni * 16 + r) * BK + sl];
    }

    __builtin_amdgcn_s_setprio(1);
#pragma unroll
    for (int kh = 0; kh < 2; ++kh)
#pragma unroll
      for (int mi = 0; mi < 4; ++mi)
#pragma unroll
        for (int ni = 0; ni < 3; ++ni)
          acc[mi][ni] = __builtin_amdgcn_mfma_f32_16x16x32_f16(af[kh][mi], bf[kh][ni],
                                                               acc[mi][ni], 0, 0, 0);
    __builtin_amdgcn_s_setprio(0);

    if (t < NKT - 1) {
      if (t + 2 < NKT) {
        // own reads done (write-protect) + own stage(t+1) landed (5 newest = stage(t+2))
        asm volatile("s_waitcnt lgkmcnt(0) vmcnt(5)" ::: "memory");
      } else {
        asm volatile("s_waitcnt lgkmcnt(0) vmcnt(0)" ::: "memory");  // last tile landed
      }
      __builtin_amdgcn_sched_barrier(0);
      __builtin_amdgcn_s_barrier();
    }
  }

#undef STAGE_A
#undef STAGE_B

  // epilogue: D mapping col = lane&15, row = q*4 + reg; bias fused
#pragma unroll
  for (int mi = 0; mi < 4; ++mi) {
#pragma unroll
    for (int ni = 0; ni < 3; ++ni) {
      const int gcol = n0 + wn + ni * 16 + r;
      const float bv = bias[gcol];
#pragma unroll
      for (int rg = 0; rg < 4; ++rg) {
        const int grow = m0 + wm + mi * 16 + q * 4 + rg;
        out[(size_t)grow * DOUT + gcol] = acc[mi][ni][rg] + bv;
      }
    }
  }
}

extern "C" void kernel_launch(void* const* d_in, const int* in_sizes, int n_in,
                              void* d_out, int out_size, void* d_ws, size_t ws_size,
                              hipStream_t stream) {
  const float* x = (const float*)d_in[0];           // (4,2048,768)
  const float* coef = (const float*)d_in[1];        // (768,768,6)
  const float* scale_base = (const float*)d_in[2];  // (768,768)
  const float* scale_sp = (const float*)d_in[3];    // (768,768)
  const float* bias = (const float*)d_in[4];        // (768,)
  float* out = (float*)d_out;                       // (8192,768)

  f16* Aa = (f16*)d_ws;                                     // 8192*5376*2 = 88.1 MB
  f16* Wa = (f16*)((char*)d_ws + (size_t)NTOK * KAUG * 2);  // 768*5376*2  = 8.3 MB

  build_AW<<<NBLK_A + NBLK_W, 256, 0, stream>>>(x, scale_base, scale_sp, coef, Aa, Wa);
  kan_gemm<<<NBLK, 512, 0, stream>>>(Aa, Wa, bias, out);
}